// Round 7
// baseline (332.482 us; speedup 1.0000x reference)
//
#include <hip/hip_runtime.h>
#include <hip/hip_bf16.h>

typedef unsigned short u16;
typedef __attribute__((ext_vector_type(8))) short short8;
typedef __attribute__((ext_vector_type(4))) float floatx4;

// ---------- helpers ----------
__device__ __forceinline__ u16 f2bf(float f) {
    union { float f; unsigned u; } v; v.f = f;
    unsigned r = v.u + 0x7fffu + ((v.u >> 16) & 1u);   // RNE
    return (u16)(r >> 16);
}
__device__ __forceinline__ float fexp2(float x) {
#if __has_builtin(__builtin_amdgcn_exp2f)
    return __builtin_amdgcn_exp2f(x);
#else
    return exp2f(x);
#endif
}
// pack two f32 -> 2xbf16 (RNE), lo = first arg
__device__ __forceinline__ unsigned cvtpk_bf16(float lo, float hi) {
    unsigned r;
    asm("v_cvt_pk_bf16_f32 %0, %1, %2" : "=v"(r) : "v"(lo), "v"(hi));
    return r;
}
// a[32:63] <-> b[0:31]
__device__ __forceinline__ void permlane32_swap(unsigned &a, unsigned &b) {
    asm("v_permlane32_swap_b32 %0, %1" : "+v"(a), "+v"(b));
}
// a[16:31]<->b[0:15], a[48:63]<->b[32:47]
__device__ __forceinline__ void permlane16_swap(unsigned &a, unsigned &b) {
    asm("v_permlane16_swap_b32 %0, %1" : "+v"(a), "+v"(b));
}

// async global->LDS, 16B per lane. LDS dest = wave-uniform base + lane*16.
__device__ __forceinline__ void async_load16(const void* g, void* l) {
    __builtin_amdgcn_global_load_lds(
        (const __attribute__((address_space(1))) unsigned int*)g,
        (__attribute__((address_space(3))) unsigned int*)l, 16, 0, 0);
}

#define B_   4
#define T_   2048
#define NH_  16
#define HD_  64
#define DIM_ 1024
#define M_   (B_ * T_)          // 8192
#define NQKV (3 * DIM_)         // 3072
#define NT_  16                 // K tiles of 64 (K = 1024)
#define LOG2E 1.4426950408889634f

// =====================================================================
// Fused preprocessing (1 launch): cvt_x | Wqkv-T | Wproj-T | rope tables
// =====================================================================
__global__ __launch_bounds__(256) void preproc(const float* __restrict__ x,
                                               const float* __restrict__ Wqkv,
                                               const float* __restrict__ Wproj,
                                               u16* __restrict__ xb,
                                               u16* __restrict__ wqt,
                                               u16* __restrict__ wpt,
                                               float* __restrict__ tabc,
                                               float* __restrict__ tabs) {
    __shared__ float tile[32][33];
    const int bid = blockIdx.x, tid = threadIdx.x;
    if (bid < 8192) {                                  // ---- cvt_x ----
        int idx = bid * 256 + tid;
        float4 v = ((const float4*)x)[idx];
        ushort4 o;
        o.x = f2bf(v.x); o.y = f2bf(v.y); o.z = f2bf(v.z); o.w = f2bf(v.w);
        ((ushort4*)xb)[idx] = o;
    } else if (bid < 12288) {                          // ---- weight transposes ----
        const float* in; u16* outp; int Cn, bx, by;
        if (bid < 11264) { int blk = bid - 8192;  in = Wqkv;  outp = wqt; Cn = NQKV; bx = blk % 96; by = blk / 96; }
        else             { int blk = bid - 11264; in = Wproj; outp = wpt; Cn = DIM_; bx = blk & 31; by = blk >> 5; }
        const int R = DIM_;
        int c0 = bx * 32, r0 = by * 32;
        int tx = tid & 31, ty = tid >> 5;              // 32 x 8
#pragma unroll
        for (int i = 0; i < 4; ++i)
            tile[ty + i * 8][tx] = in[(size_t)(r0 + ty + i * 8) * Cn + c0 + tx];
        __syncthreads();
#pragma unroll
        for (int i = 0; i < 4; ++i)
            outp[(size_t)(c0 + ty + i * 8) * R + r0 + tx] = f2bf(tile[tx][ty + i * 8]);
    } else {                                           // ---- rope tables ----
        int idx = (bid - 12288) * 256 + tid;
        int t = idx >> 5, j = idx & 31;
        double invf = pow(10000.0, -(double)j / 32.0);
        double th = (double)t * invf;
        tabc[idx] = (float)cos(th);
        tabs[idx] = (float)sin(th);
    }
}

// =====================================================================
// Pipelined 128x256 GEMM core (T3+T4+T5): 8 waves, BK=64, triple-buffered
// LDS, 2 phases/K-tile, counted vmcnt(6) at tile boundaries.
// =====================================================================
__device__ __forceinline__ void gemm_core(const u16* __restrict__ A,
                                          const u16* __restrict__ Bt,
                                          u16* smem, int m0, int n0, int tid,
                                          floatx4 (&acc)[4][4]) {
    const int wave = tid >> 6, lane = tid & 63;
    const int ln15 = lane & 15, quad = lane >> 4;
    const int wm = (wave & 1) * 64, wn = (wave >> 1) * 64;
    const int l8 = lane & 7, ld8 = lane >> 3;
    const int sgc = (l8 ^ ld8) * 8;                    // swizzled source col (u16)
    const int K = DIM_;

    const u16* aS = A + (size_t)(m0 + wave * 16 + ld8) * K + sgc;
    const u16* bS = Bt + (size_t)(n0 + wave * 32 + ld8) * K + sgc;

    auto issueA_B0 = [&](int k2, u16* As2, u16* Bs2) {   // 3 loads
        async_load16(aS + k2,          As2 + (wave * 16) * 64);
        async_load16(aS + 8 * K + k2,  As2 + (wave * 16 + 8) * 64);
        async_load16(bS + k2,          Bs2 + (wave * 32) * 64);
    };
    auto issueB123 = [&](int k2, u16* Bs2) {             // 3 loads
        async_load16(bS + 8 * K + k2,  Bs2 + (wave * 32 + 8) * 64);
        async_load16(bS + 16 * K + k2, Bs2 + (wave * 32 + 16) * 64);
        async_load16(bS + 24 * K + k2, Bs2 + (wave * 32 + 24) * 64);
    };
    auto compute = [&](const u16* As_c, const u16* Bs_c, int c4) {
        short8 af[4], bfv[4];
#pragma unroll
        for (int i = 0; i < 4; ++i) {
            int row = wm + i * 16 + ln15;
            af[i] = *(const short8*)&As_c[row * 64 + (((c4 + quad) ^ (row & 7)) << 3)];
        }
#pragma unroll
        for (int j = 0; j < 4; ++j) {
            int row = wn + j * 16 + ln15;
            bfv[j] = *(const short8*)&Bs_c[row * 64 + (((c4 + quad) ^ (row & 7)) << 3)];
        }
        __builtin_amdgcn_s_setprio(1);
#pragma unroll
        for (int i = 0; i < 4; ++i)
#pragma unroll
            for (int j = 0; j < 4; ++j)
                acc[i][j] = __builtin_amdgcn_mfma_f32_16x16x32_bf16(
                    af[i], bfv[j], acc[i][j], 0, 0, 0);
        __builtin_amdgcn_s_setprio(0);
    };

    // prologue: stage tiles 0 and 1 (12 loads/thread in flight)
    issueA_B0(0, smem, smem + 24576);
    issueB123(0, smem + 24576);
    issueA_B0(64, smem + 8192, smem + 24576 + 16384);
    issueB123(64, smem + 24576 + 16384);

#pragma unroll 1
    for (int t = 0; t < NT_; ++t) {
        if (t < NT_ - 1) asm volatile("s_waitcnt vmcnt(6)" ::: "memory");
        else             asm volatile("s_waitcnt vmcnt(0)" ::: "memory");
        __builtin_amdgcn_s_barrier();
        asm volatile("" ::: "memory");

        const int cb = t % 3, cb2 = (t + 2) % 3;
        const u16* As_c = smem + cb * 8192;
        const u16* Bs_c = smem + 24576 + cb * 16384;
        u16* As2 = smem + cb2 * 8192;
        u16* Bs2 = smem + 24576 + cb2 * 16384;
        const bool iss = t < NT_ - 2;
        const int k2 = (t + 2) * 64;

        if (iss) issueA_B0(k2, As2, Bs2);
        compute(As_c, Bs_c, 0);
        asm volatile("" ::: "memory");
        __builtin_amdgcn_s_barrier();
        asm volatile("" ::: "memory");

        if (iss) issueB123(k2, Bs2);
        compute(As_c, Bs_c, 4);
        asm volatile("" ::: "memory");
    }
}

// ---------- qkv GEMM with fused RoPE/split + DIRECT V-transpose ----------
__global__ __launch_bounds__(512, 2) void gemm_qkv(const u16* __restrict__ A,
                                                   const u16* __restrict__ Bt,
                                                   const float* __restrict__ tabc,
                                                   const float* __restrict__ tabs,
                                                   u16* __restrict__ Qo,
                                                   u16* __restrict__ Ko,
                                                   u16* __restrict__ Vt) {
    __shared__ __align__(16) u16 smem[73728];          // 144 KB: 3x(A 16K + B 32K)
    const int tid = threadIdx.x;
    const int bid = blockIdx.x;
    const int wg = (bid & 7) * 96 + (bid >> 3);        // XCD-contiguous
    const int bx = wg / 64, by = wg - bx * 64;         // bx 0..11, by 0..63
    const int m0 = by * 128, n0 = bx * 256;

    floatx4 acc[4][4] = {};
    gemm_core(A, Bt, smem, m0, n0, tid, acc);

    const int wave = tid >> 6, lane = tid & 63;
    const int ln15 = lane & 15, quad = lane >> 4;
    const int wm = (wave & 1) * 64, wn = (wave >> 1) * 64;

    __syncthreads();                                   // all tile reads done; reuse smem
    u16* Es = smem;                                    // [128][256] logical
    const int sel = n0 >> 10;                          // 0=q, 1=k, 2=v
    auto es_put = [&](int row, int col, u16 v) {
        int c = col >> 3;
        int pc = (c & 24) | ((c & 7) ^ (row & 7));
        Es[row * 256 + pc * 8 + (col & 7)] = v;
    };
    if (sel == 2) {
#pragma unroll
        for (int i = 0; i < 4; ++i)
#pragma unroll
            for (int j = 0; j < 4; ++j)
#pragma unroll
                for (int r = 0; r < 4; ++r)
                    es_put(wm + i * 16 + quad * 4 + r, wn + j * 16 + ln15,
                           f2bf(acc[i][j][r]));
    } else {
        const float scale = sel ? 1.0f : 0.125f * LOG2E;
#pragma unroll
        for (int i = 0; i < 4; ++i)
#pragma unroll
            for (int jjl = 0; jjl < 2; ++jjl) {
                int j = jjl * 16 + ln15;               // d in [0,32)
#pragma unroll
                for (int r = 0; r < 4; ++r) {
                    int row = wm + i * 16 + quad * 4 + r;
                    int t = (m0 + row) & (T_ - 1);
                    float cs = tabc[t * 32 + j], sn = tabs[t * 32 + j];
                    float xl = acc[i][jjl][r], xh = acc[i][jjl + 2][r];
                    es_put(row, wn + j,      f2bf((xl * cs - xh * sn) * scale));
                    es_put(row, wn + j + 32, f2bf((xh * cs + xl * sn) * scale));
                }
            }
    }
    __syncthreads();
    if (sel == 2) {
        // ---- direct Vt[bh][d][t] write from Es (lo/hi dword split) ----
        const int bq = m0 >> 11;
        const int t0 = m0 & (T_ - 1);
        const int h0 = (n0 & 1023) >> 6;               // 0,4,8,12
#pragma unroll
        for (int a = 0; a < 4; ++a) {
            int aid = tid + a * 512;                   // 0..2047
            int hh = aid >> 9;                         // head-in-tile 0..3
            int rem = aid & 511;
            int tseg = rem >> 5;                       // 0..15 (t block of 8)
            int d2 = rem & 31;                         // dword col in head
            int col = hh * 64 + 2 * d2;
            int cch = col >> 3;
            u16 lo8[8], hi8[8];
#pragma unroll
            for (int j = 0; j < 8; ++j) {
                int row = tseg * 8 + j;
                int pc = (cch & 24) | ((cch & 7) ^ (row & 7));
                unsigned w = *(const unsigned*)&Es[row * 256 + pc * 8 + (col & 7)];
                lo8[j] = (u16)(w & 0xffffu);
                hi8[j] = (u16)(w >> 16);
            }
            size_t ob = ((size_t)((bq * NH_ + h0 + hh) * HD_) + 2 * d2) * T_ + t0 + tseg * 8;
            *(uint4*)(Vt + ob) = *(const uint4*)lo8;
            *(uint4*)(Vt + ob + T_) = *(const uint4*)hi8;
        }
    } else {
        const int bb = m0 >> 11;
        u16* outqk = (sel == 1) ? Ko : Qo;
#pragma unroll
        for (int k = 0; k < 8; ++k) {
            int cid = tid + k * 512;                   // 0..4095
            int row = cid >> 5, c = cid & 31;          // logical chunk 0..31
            int pc = (c & 24) | ((c & 7) ^ (row & 7));
            uint4 v = *(const uint4*)&Es[row * 256 + pc * 8];
            int h = ((n0 & 1023) >> 6) + (c >> 3);
            int d = (c & 7) * 8;
            int t = (m0 + row) & (T_ - 1);
            *(uint4*)&outqk[((size_t)(bb * NH_ + h) * T_ + t) * HD_ + d] = v;
        }
    }
}

// =====================================================================
// 128x128 GEMM core, 4 waves, BK=64, double-buffered 64 KB LDS.
// =====================================================================
__device__ __forceinline__ void gemm_core128(const u16* __restrict__ A,
                                             const u16* __restrict__ Bt,
                                             u16* smem, int m0, int n0, int tid,
                                             floatx4 (&acc)[4][4]) {
    const int wave = tid >> 6, lane = tid & 63;
    const int ln15 = lane & 15, quad = lane >> 4;
    const int wm = (wave & 1) * 64, wn = (wave >> 1) * 64;
    const int l8 = lane & 7, ld8 = lane >> 3;
    const int sgc = (l8 ^ ld8) * 8;
    const int K = DIM_;

    const u16* aS = A + (size_t)(m0 + wave * 32 + ld8) * K + sgc;
    const u16* bS = Bt + (size_t)(n0 + wave * 32 + ld8) * K + sgc;

    auto stage = [&](int k0, u16* buf) {               // 8 loads/thread
#pragma unroll
        for (int it = 0; it < 4; ++it) {
            async_load16(aS + (size_t)(it * 8) * K + k0,
                         buf + (wave * 32 + it * 8) * 64);
            async_load16(bS + (size_t)(it * 8) * K + k0,
                         buf + 8192 + (wave * 32 + it * 8) * 64);
        }
    };
    auto compute = [&](const u16* buf, int c4) {
        short8 af[4], bfv[4];
#pragma unroll
        for (int i = 0; i < 4; ++i) {
            int row = wm + i * 16 + ln15;
            af[i] = *(const short8*)&buf[row * 64 + (((c4 + quad) ^ (row & 7)) << 3)];
        }
#pragma unroll
        for (int j = 0; j < 4; ++j) {
            int row = wn + j * 16 + ln15;
            bfv[j] = *(const short8*)&buf[8192 + row * 64 + (((c4 + quad) ^ (row & 7)) << 3)];
        }
        __builtin_amdgcn_s_setprio(1);
#pragma unroll
        for (int i = 0; i < 4; ++i)
#pragma unroll
            for (int j = 0; j < 4; ++j)
                acc[i][j] = __builtin_amdgcn_mfma_f32_16x16x32_bf16(
                    af[i], bfv[j], acc[i][j], 0, 0, 0);
        __builtin_amdgcn_s_setprio(0);
    };

    stage(0, smem);
#pragma unroll 1
    for (int t = 0; t < NT_; ++t) {
        asm volatile("s_waitcnt vmcnt(0)" ::: "memory");
        __builtin_amdgcn_s_barrier();
        asm volatile("" ::: "memory");
        if (t + 1 < NT_) stage((t + 1) * 64, smem + ((t + 1) & 1) * 16384);
        const u16* cur = smem + (t & 1) * 16384;
        compute(cur, 0);
        compute(cur, 4);
        asm volatile("" ::: "memory");
    }
}

// ---------- out-proj GEMM, 128x128 core, f32 output ----------
__global__ __launch_bounds__(256, 4) void gemm_proj(const u16* __restrict__ A,
                                                    const u16* __restrict__ Bt,
                                                    float* __restrict__ C) {
    __shared__ __align__(16) u16 smem[32768];
    const int tid = threadIdx.x;
    const int bid = blockIdx.x;
    const int local = bid >> 3;                        // 0..63
    const int by = (bid & 7) * 8 + (local & 7);        // row-block 0..63
    const int bx = local >> 3;                         // col-block 0..7
    const int m0 = by * 128, n0 = bx * 128;

    floatx4 acc[4][4] = {};
    gemm_core128(A, Bt, smem, m0, n0, tid, acc);

    const int wave = tid >> 6, lane = tid & 63;
    const int ln15 = lane & 15, quad = lane >> 4;
    const int wm = (wave & 1) * 64, wn = (wave >> 1) * 64;
#pragma unroll
    for (int i = 0; i < 4; ++i)
#pragma unroll
        for (int jj = 0; jj < 4; ++jj)
#pragma unroll
            for (int r = 0; r < 4; ++r) {
                int m = m0 + wm + i * 16 + quad * 4 + r;
                int n = n0 + wn + jj * 16 + ln15;
                C[(size_t)m * DIM_ + n] = acc[i][jj][r];
            }
}

// ---------- flash attention: LDS-FREE, barrier-free k-loop ----------
// K/V MFMA fragments are read DIRECTLY from global (per-row the 4 quads
// form one contiguous 64B line -> fully-coalesced 16x64B per load).
// Per-block working set = 8KB K-tile + 8KB V-tile -> L1-resident; the
// bid mapping pins each XCD to 8 bh (= 4MB K+V = its L2). No barriers ->
// each wave independent; compiler pipelines next-kf/vf loads under
// compute. Heavy tiles (tidx=15, 32 k-steps) dispatch first; light ones
// backfill the tail. 1024 blocks x 4 waves = 16 waves/CU co-resident.
__global__ __launch_bounds__(256, 4) void attn_kernel(const u16* __restrict__ Q,
                                                      const u16* __restrict__ Kh,
                                                      const u16* __restrict__ Vt,
                                                      u16* __restrict__ Y) {
    const int tid = threadIdx.x, wave = tid >> 6, lane = tid & 63;
    const int ln15 = lane & 15, quad = lane >> 4;
    const int bid = blockIdx.x;
    const int tidx = 15 - (bid >> 6);                  // heavy-first
    const int bh = bid & 63;                           // XCD x <-> bh = x mod 8 set
    const int b = bh >> 4, h = bh & 15;

    const u16* kbase = Kh + (size_t)bh * T_ * HD_;
    const u16* vbase = Vt + (size_t)bh * HD_ * T_;
    const short8 ones = {0x3F80, 0x3F80, 0x3F80, 0x3F80,
                         0x3F80, 0x3F80, 0x3F80, 0x3F80};

    const int base_row = tidx * 128 + wave * 32;       // wave owns 32 q-rows

    const u16* qp0 = Q + ((size_t)bh * T_ + base_row + ln15) * HD_;
    const u16* qp1 = qp0 + 16 * HD_;
    short8 qf00 = *(const short8*)(qp0 + quad * 8);
    short8 qf01 = *(const short8*)(qp0 + 32 + quad * 8);
    short8 qf10 = *(const short8*)(qp1 + quad * 8);
    short8 qf11 = *(const short8*)(qp1 + 32 + quad * 8);

    floatx4 o0[5] = {}, o1[5] = {};                    // per-group: 4 d-cols + rowsum

    const int NKT = 2 * tidx + 1;                      // last k-tile index
    for (int kt = 0; kt <= NKT; ++kt) {
        // ---- K fragments direct from global (L1-hit after first wave) ----
        floatx4 s0[4] = {}, s1[4] = {};
        __builtin_amdgcn_s_setprio(1);
#pragma unroll
        for (int nt = 0; nt < 4; ++nt) {
            const u16* kp = kbase + (size_t)(kt * 64 + nt * 16 + ln15) * HD_;
            short8 kf0 = *(const short8*)(kp + quad * 8);
            short8 kf1 = *(const short8*)(kp + 32 + quad * 8);
            s0[nt] = __builtin_amdgcn_mfma_f32_16x16x32_bf16(kf0, qf00, s0[nt], 0, 0, 0);
            s0[nt] = __builtin_amdgcn_mfma_f32_16x16x32_bf16(kf1, qf01, s0[nt], 0, 0, 0);
            s1[nt] = __builtin_amdgcn_mfma_f32_16x16x32_bf16(kf0, qf10, s1[nt], 0, 0, 0);
            s1[nt] = __builtin_amdgcn_mfma_f32_16x16x32_bf16(kf1, qf11, s1[nt], 0, 0, 0);
        }
        __builtin_amdgcn_s_setprio(0);
        // ---- mask + exp2 ----
        if (kt >= 2 * tidx) {                          // diagonal 128-row band
            const int koff = (kt - 2 * tidx) * 64;
            const int lim0 = wave * 32 + ln15;         // local q-row, group 0
#pragma unroll
            for (int nt = 0; nt < 4; ++nt) {
                int key = koff + nt * 16 + quad * 4;
#pragma unroll
                for (int r = 0; r < 4; ++r) {
                    s0[nt][r] = (key + r > lim0) ? 0.f : fexp2(s0[nt][r]);
                    s1[nt][r] = (key + r > lim0 + 16) ? 0.f : fexp2(s1[nt][r]);
                }
            }
        } else {
#pragma unroll
            for (int nt = 0; nt < 4; ++nt)
#pragma unroll
                for (int r = 0; r < 4; ++r) {
                    s0[nt][r] = fexp2(s0[nt][r]);
                    s1[nt][r] = fexp2(s1[nt][r]);
                }
        }
        // ---- in-register C/D -> A-operand transform, group 0 then 1 ----
        union { unsigned u[4]; short8 s8; } pa0, pb0, pa1, pb1;
        {
            unsigned x0 = cvtpk_bf16(s0[0][0], s0[0][1]);
            unsigned x1 = cvtpk_bf16(s0[1][0], s0[1][1]);
            unsigned y0 = cvtpk_bf16(s0[0][2], s0[0][3]);
            unsigned y1 = cvtpk_bf16(s0[1][2], s0[1][3]);
            unsigned x2 = cvtpk_bf16(s0[2][0], s0[2][1]);
            unsigned x3 = cvtpk_bf16(s0[3][0], s0[3][1]);
            unsigned y2 = cvtpk_bf16(s0[2][2], s0[2][3]);
            unsigned y3 = cvtpk_bf16(s0[3][2], s0[3][3]);
            permlane32_swap(x0, x1); permlane16_swap(x0, x1);
            permlane32_swap(y0, y1); permlane16_swap(y0, y1);
            permlane32_swap(x2, x3); permlane16_swap(x2, x3);
            permlane32_swap(y2, y3); permlane16_swap(y2, y3);
            pa0.u[0] = x0; pa0.u[1] = y0; pa0.u[2] = x1; pa0.u[3] = y1;
            pb0.u[0] = x2; pb0.u[1] = y2; pb0.u[2] = x3; pb0.u[3] = y3;
        }
        {
            unsigned x0 = cvtpk_bf16(s1[0][0], s1[0][1]);
            unsigned x1 = cvtpk_bf16(s1[1][0], s1[1][1]);
            unsigned y0 = cvtpk_bf16(s1[0][2], s1[0][3]);
            unsigned y1 = cvtpk_bf16(s1[1][2], s1[1][3]);
            unsigned x2 = cvtpk_bf16(s1[2][0], s1[2][1]);
            unsigned x3 = cvtpk_bf16(s1[3][0], s1[3][1]);
            unsigned y2 = cvtpk_bf16(s1[2][2], s1[2][3]);
            unsigned y3 = cvtpk_bf16(s1[3][2], s1[3][3]);
            permlane32_swap(x0, x1); permlane16_swap(x0, x1);
            permlane32_swap(y0, y1); permlane16_swap(y0, y1);
            permlane32_swap(x2, x3); permlane16_swap(x2, x3);
            permlane32_swap(y2, y3); permlane16_swap(y2, y3);
            pa1.u[0] = x0; pa1.u[1] = y0; pa1.u[2] = x1; pa1.u[3] = y1;
            pb1.u[0] = x2; pb1.u[1] = y2; pb1.u[2] = x3; pb1.u[3] = y3;
        }
        // ---- V fragments direct from global; PV + rowsum ----
        __builtin_amdgcn_s_setprio(1);
#pragma unroll
        for (int nt = 0; nt < 4; ++nt) {
            const u16* vp = vbase + (size_t)(nt * 16 + ln15) * T_ + kt * 64;
            short8 vf0 = *(const short8*)(vp + quad * 8);
            short8 vf1 = *(const short8*)(vp + 32 + quad * 8);
            o0[nt] = __builtin_amdgcn_mfma_f32_16x16x32_bf16(pa0.s8, vf0, o0[nt], 0, 0, 0);
            o0[nt] = __builtin_amdgcn_mfma_f32_16x16x32_bf16(pb0.s8, vf1, o0[nt], 0, 0, 0);
            o1[nt] = __builtin_amdgcn_mfma_f32_16x16x32_bf16(pa1.s8, vf0, o1[nt], 0, 0, 0);
            o1[nt] = __builtin_amdgcn_mfma_f32_16x16x32_bf16(pb1.s8, vf1, o1[nt], 0, 0, 0);
        }
        o0[4] = __builtin_amdgcn_mfma_f32_16x16x32_bf16(pa0.s8, ones, o0[4], 0, 0, 0);
        o0[4] = __builtin_amdgcn_mfma_f32_16x16x32_bf16(pb0.s8, ones, o0[4], 0, 0, 0);
        o1[4] = __builtin_amdgcn_mfma_f32_16x16x32_bf16(pa1.s8, ones, o1[4], 0, 0, 0);
        o1[4] = __builtin_amdgcn_mfma_f32_16x16x32_bf16(pb1.s8, ones, o1[4], 0, 0, 0);
        __builtin_amdgcn_s_setprio(0);
    }
    // ---- normalize + store both groups ----
#pragma unroll
    for (int r = 0; r < 4; ++r) {
        float inv0 = 1.f / o0[4][r];
        int row0 = base_row + quad * 4 + r;
        u16* yp0 = Y + ((size_t)(b * T_ + row0)) * DIM_ + h * HD_;
#pragma unroll
        for (int nt = 0; nt < 4; ++nt)
            yp0[nt * 16 + ln15] = f2bf(o0[nt][r] * inv0);
        float inv1 = 1.f / o1[4][r];
        u16* yp1 = yp0 + (size_t)16 * DIM_;
#pragma unroll
        for (int nt = 0; nt < 4; ++nt)
            yp1[nt * 16 + ln15] = f2bf(o1[nt][r] * inv1);
    }
}

// ---------- launch ----------
extern "C" void kernel_launch(void* const* d_in, const int* in_sizes, int n_in,
                              void* d_out, int out_size, void* d_ws, size_t ws_size,
                              hipStream_t stream) {
    const float* x     = (const float*)d_in[0];
    const float* Wqkv  = (const float*)d_in[1];
    const float* Wproj = (const float*)d_in[2];
    float* out = (float*)d_out;
    char* ws = (char*)d_ws;

    const size_t SZ_XB  = (size_t)M_ * DIM_ * 2;       // 16 MB
    const size_t SZ_WQT = (size_t)NQKV * DIM_ * 2;     // 6 MB
    const size_t SZ_WPT = (size_t)DIM_ * DIM_ * 2;     // 2 MB
    const size_t SZ_Q   = SZ_XB;                       // 16 MB each: Q,K,(unused),Vt
    const size_t SZ_TAB = (size_t)T_ * 32 * 4;         // 256 KB

    u16*   xb   = (u16*)(ws);
    u16*   wqt  = (u16*)(ws + SZ_XB);
    u16*   wpt  = (u16*)(ws + SZ_XB + SZ_WQT);
    u16*   qb   = (u16*)(ws + SZ_XB + SZ_WQT + SZ_WPT);
    u16*   kb   = (u16*)(ws + SZ_XB + SZ_WQT + SZ_WPT + SZ_Q);
    u16*   vtb  = (u16*)(ws + SZ_XB + SZ_WQT + SZ_WPT + 3 * SZ_Q);
    float* tabc = (float*)(ws + SZ_XB + SZ_WQT + SZ_WPT + 4 * SZ_Q);
    float* tabs = (float*)(ws + SZ_XB + SZ_WQT + SZ_WPT + 4 * SZ_Q + SZ_TAB);
    u16*   yb   = xb;                                  // reuse xb after qkv GEMM

    // fused preprocessing (1 launch instead of 4)
    preproc<<<12544, 256, 0, stream>>>(x, Wqkv, Wproj, xb, wqt, wpt, tabc, tabs);
    // 768 blocks = 3 full epochs at 1 block/CU; writes Vt directly
    gemm_qkv<<<768, 512, 0, stream>>>(xb, wqt, tabc, tabs, qb, kb, vtb);
    // 1024 blocks (16 tiles x 64 bh), LDS-free, heavy tiles first
    attn_kernel<<<1024, 256, 0, stream>>>(qb, kb, vtb, yb);
    // 512 blocks = exactly 1 fill round at 2 blocks/CU
    gemm_proj<<<512, 256, 0, stream>>>(yb, wpt, out);
}

// Round 8
// 231.274 us; speedup vs baseline: 1.4376x; 1.4376x over previous
//
#include <hip/hip_runtime.h>
#include <hip/hip_bf16.h>

typedef unsigned short u16;
typedef __attribute__((ext_vector_type(8))) short short8;
typedef __attribute__((ext_vector_type(4))) float floatx4;

// ---------- helpers ----------
__device__ __forceinline__ u16 f2bf(float f) {
    union { float f; unsigned u; } v; v.f = f;
    unsigned r = v.u + 0x7fffu + ((v.u >> 16) & 1u);   // RNE
    return (u16)(r >> 16);
}
__device__ __forceinline__ float fexp2(float x) {
#if __has_builtin(__builtin_amdgcn_exp2f)
    return __builtin_amdgcn_exp2f(x);
#else
    return exp2f(x);
#endif
}
// pack two f32 -> 2xbf16 (RNE), lo = first arg
__device__ __forceinline__ unsigned cvtpk_bf16(float lo, float hi) {
    unsigned r;
    asm("v_cvt_pk_bf16_f32 %0, %1, %2" : "=v"(r) : "v"(lo), "v"(hi));
    return r;
}
// a[32:63] <-> b[0:31]
__device__ __forceinline__ void permlane32_swap(unsigned &a, unsigned &b) {
    asm("v_permlane32_swap_b32 %0, %1" : "+v"(a), "+v"(b));
}
// a[16:31]<->b[0:15], a[48:63]<->b[32:47]
__device__ __forceinline__ void permlane16_swap(unsigned &a, unsigned &b) {
    asm("v_permlane16_swap_b32 %0, %1" : "+v"(a), "+v"(b));
}

// async global->LDS, 16B per lane. LDS dest = wave-uniform base + lane*16.
__device__ __forceinline__ void async_load16(const void* g, void* l) {
    __builtin_amdgcn_global_load_lds(
        (const __attribute__((address_space(1))) unsigned int*)g,
        (__attribute__((address_space(3))) unsigned int*)l, 16, 0, 0);
}

#define B_   4
#define T_   2048
#define NH_  16
#define HD_  64
#define DIM_ 1024
#define M_   (B_ * T_)          // 8192
#define NQKV (3 * DIM_)         // 3072
#define NT_  16                 // K tiles of 64 (K = 1024)
#define LOG2E 1.4426950408889634f

// =====================================================================
// Fused preprocessing (1 launch): cvt_x | Wqkv-T | Wproj-T | rope tables
// =====================================================================
__global__ __launch_bounds__(256) void preproc(const float* __restrict__ x,
                                               const float* __restrict__ Wqkv,
                                               const float* __restrict__ Wproj,
                                               u16* __restrict__ xb,
                                               u16* __restrict__ wqt,
                                               u16* __restrict__ wpt,
                                               float* __restrict__ tabc,
                                               float* __restrict__ tabs) {
    __shared__ float tile[32][33];
    const int bid = blockIdx.x, tid = threadIdx.x;
    if (bid < 8192) {                                  // ---- cvt_x ----
        int idx = bid * 256 + tid;
        float4 v = ((const float4*)x)[idx];
        ushort4 o;
        o.x = f2bf(v.x); o.y = f2bf(v.y); o.z = f2bf(v.z); o.w = f2bf(v.w);
        ((ushort4*)xb)[idx] = o;
    } else if (bid < 12288) {                          // ---- weight transposes ----
        const float* in; u16* outp; int Cn, bx, by;
        if (bid < 11264) { int blk = bid - 8192;  in = Wqkv;  outp = wqt; Cn = NQKV; bx = blk % 96; by = blk / 96; }
        else             { int blk = bid - 11264; in = Wproj; outp = wpt; Cn = DIM_; bx = blk & 31; by = blk >> 5; }
        const int R = DIM_;
        int c0 = bx * 32, r0 = by * 32;
        int tx = tid & 31, ty = tid >> 5;              // 32 x 8
#pragma unroll
        for (int i = 0; i < 4; ++i)
            tile[ty + i * 8][tx] = in[(size_t)(r0 + ty + i * 8) * Cn + c0 + tx];
        __syncthreads();
#pragma unroll
        for (int i = 0; i < 4; ++i)
            outp[(size_t)(c0 + ty + i * 8) * R + r0 + tx] = f2bf(tile[tx][ty + i * 8]);
    } else {                                           // ---- rope tables ----
        int idx = (bid - 12288) * 256 + tid;
        int t = idx >> 5, j = idx & 31;
        double invf = pow(10000.0, -(double)j / 32.0);
        double th = (double)t * invf;
        tabc[idx] = (float)cos(th);
        tabs[idx] = (float)sin(th);
    }
}

// =====================================================================
// Pipelined 128x256 GEMM core (T3+T4+T5): 8 waves, BK=64, triple-buffered
// LDS, 2 phases/K-tile, counted vmcnt(6) at tile boundaries.
// =====================================================================
__device__ __forceinline__ void gemm_core(const u16* __restrict__ A,
                                          const u16* __restrict__ Bt,
                                          u16* smem, int m0, int n0, int tid,
                                          floatx4 (&acc)[4][4]) {
    const int wave = tid >> 6, lane = tid & 63;
    const int ln15 = lane & 15, quad = lane >> 4;
    const int wm = (wave & 1) * 64, wn = (wave >> 1) * 64;
    const int l8 = lane & 7, ld8 = lane >> 3;
    const int sgc = (l8 ^ ld8) * 8;                    // swizzled source col (u16)
    const int K = DIM_;

    const u16* aS = A + (size_t)(m0 + wave * 16 + ld8) * K + sgc;
    const u16* bS = Bt + (size_t)(n0 + wave * 32 + ld8) * K + sgc;

    auto issueA_B0 = [&](int k2, u16* As2, u16* Bs2) {   // 3 loads
        async_load16(aS + k2,          As2 + (wave * 16) * 64);
        async_load16(aS + 8 * K + k2,  As2 + (wave * 16 + 8) * 64);
        async_load16(bS + k2,          Bs2 + (wave * 32) * 64);
    };
    auto issueB123 = [&](int k2, u16* Bs2) {             // 3 loads
        async_load16(bS + 8 * K + k2,  Bs2 + (wave * 32 + 8) * 64);
        async_load16(bS + 16 * K + k2, Bs2 + (wave * 32 + 16) * 64);
        async_load16(bS + 24 * K + k2, Bs2 + (wave * 32 + 24) * 64);
    };
    auto compute = [&](const u16* As_c, const u16* Bs_c, int c4) {
        short8 af[4], bfv[4];
#pragma unroll
        for (int i = 0; i < 4; ++i) {
            int row = wm + i * 16 + ln15;
            af[i] = *(const short8*)&As_c[row * 64 + (((c4 + quad) ^ (row & 7)) << 3)];
        }
#pragma unroll
        for (int j = 0; j < 4; ++j) {
            int row = wn + j * 16 + ln15;
            bfv[j] = *(const short8*)&Bs_c[row * 64 + (((c4 + quad) ^ (row & 7)) << 3)];
        }
        __builtin_amdgcn_s_setprio(1);
#pragma unroll
        for (int i = 0; i < 4; ++i)
#pragma unroll
            for (int j = 0; j < 4; ++j)
                acc[i][j] = __builtin_amdgcn_mfma_f32_16x16x32_bf16(
                    af[i], bfv[j], acc[i][j], 0, 0, 0);
        __builtin_amdgcn_s_setprio(0);
    };

    // prologue: stage tiles 0 and 1 (12 loads/thread in flight)
    issueA_B0(0, smem, smem + 24576);
    issueB123(0, smem + 24576);
    issueA_B0(64, smem + 8192, smem + 24576 + 16384);
    issueB123(64, smem + 24576 + 16384);

#pragma unroll 1
    for (int t = 0; t < NT_; ++t) {
        if (t < NT_ - 1) asm volatile("s_waitcnt vmcnt(6)" ::: "memory");
        else             asm volatile("s_waitcnt vmcnt(0)" ::: "memory");
        __builtin_amdgcn_s_barrier();
        asm volatile("" ::: "memory");

        const int cb = t % 3, cb2 = (t + 2) % 3;
        const u16* As_c = smem + cb * 8192;
        const u16* Bs_c = smem + 24576 + cb * 16384;
        u16* As2 = smem + cb2 * 8192;
        u16* Bs2 = smem + 24576 + cb2 * 16384;
        const bool iss = t < NT_ - 2;
        const int k2 = (t + 2) * 64;

        if (iss) issueA_B0(k2, As2, Bs2);
        compute(As_c, Bs_c, 0);
        asm volatile("" ::: "memory");
        __builtin_amdgcn_s_barrier();
        asm volatile("" ::: "memory");

        if (iss) issueB123(k2, Bs2);
        compute(As_c, Bs_c, 4);
        asm volatile("" ::: "memory");
    }
}

// ---------- qkv GEMM with fused RoPE/split + DIRECT V-transpose ----------
__global__ __launch_bounds__(512, 2) void gemm_qkv(const u16* __restrict__ A,
                                                   const u16* __restrict__ Bt,
                                                   const float* __restrict__ tabc,
                                                   const float* __restrict__ tabs,
                                                   u16* __restrict__ Qo,
                                                   u16* __restrict__ Ko,
                                                   u16* __restrict__ Vt) {
    __shared__ __align__(16) u16 smem[73728];          // 144 KB: 3x(A 16K + B 32K)
    const int tid = threadIdx.x;
    const int bid = blockIdx.x;
    const int wg = (bid & 7) * 96 + (bid >> 3);        // XCD-contiguous
    const int bx = wg / 64, by = wg - bx * 64;         // bx 0..11, by 0..63
    const int m0 = by * 128, n0 = bx * 256;

    floatx4 acc[4][4] = {};
    gemm_core(A, Bt, smem, m0, n0, tid, acc);

    const int wave = tid >> 6, lane = tid & 63;
    const int ln15 = lane & 15, quad = lane >> 4;
    const int wm = (wave & 1) * 64, wn = (wave >> 1) * 64;

    __syncthreads();                                   // all tile reads done; reuse smem
    u16* Es = smem;                                    // [128][256] logical
    const int sel = n0 >> 10;                          // 0=q, 1=k, 2=v
    auto es_put = [&](int row, int col, u16 v) {
        int c = col >> 3;
        int pc = (c & 24) | ((c & 7) ^ (row & 7));
        Es[row * 256 + pc * 8 + (col & 7)] = v;
    };
    if (sel == 2) {
#pragma unroll
        for (int i = 0; i < 4; ++i)
#pragma unroll
            for (int j = 0; j < 4; ++j)
#pragma unroll
                for (int r = 0; r < 4; ++r)
                    es_put(wm + i * 16 + quad * 4 + r, wn + j * 16 + ln15,
                           f2bf(acc[i][j][r]));
    } else {
        const float scale = sel ? 1.0f : 0.125f * LOG2E;
#pragma unroll
        for (int i = 0; i < 4; ++i)
#pragma unroll
            for (int jjl = 0; jjl < 2; ++jjl) {
                int j = jjl * 16 + ln15;               // d in [0,32)
#pragma unroll
                for (int r = 0; r < 4; ++r) {
                    int row = wm + i * 16 + quad * 4 + r;
                    int t = (m0 + row) & (T_ - 1);
                    float cs = tabc[t * 32 + j], sn = tabs[t * 32 + j];
                    float xl = acc[i][jjl][r], xh = acc[i][jjl + 2][r];
                    es_put(row, wn + j,      f2bf((xl * cs - xh * sn) * scale));
                    es_put(row, wn + j + 32, f2bf((xh * cs + xl * sn) * scale));
                }
            }
    }
    __syncthreads();
    if (sel == 2) {
        // ---- direct Vt[bh][d][t] write from Es (lo/hi dword split) ----
        const int bq = m0 >> 11;
        const int t0 = m0 & (T_ - 1);
        const int h0 = (n0 & 1023) >> 6;               // 0,4,8,12
#pragma unroll
        for (int a = 0; a < 4; ++a) {
            int aid = tid + a * 512;                   // 0..2047
            int hh = aid >> 9;                         // head-in-tile 0..3
            int rem = aid & 511;
            int tseg = rem >> 5;                       // 0..15 (t block of 8)
            int d2 = rem & 31;                         // dword col in head
            int col = hh * 64 + 2 * d2;
            int cch = col >> 3;
            u16 lo8[8], hi8[8];
#pragma unroll
            for (int j = 0; j < 8; ++j) {
                int row = tseg * 8 + j;
                int pc = (cch & 24) | ((cch & 7) ^ (row & 7));
                unsigned w = *(const unsigned*)&Es[row * 256 + pc * 8 + (col & 7)];
                lo8[j] = (u16)(w & 0xffffu);
                hi8[j] = (u16)(w >> 16);
            }
            size_t ob = ((size_t)((bq * NH_ + h0 + hh) * HD_) + 2 * d2) * T_ + t0 + tseg * 8;
            *(uint4*)(Vt + ob) = *(const uint4*)lo8;
            *(uint4*)(Vt + ob + T_) = *(const uint4*)hi8;
        }
    } else {
        const int bb = m0 >> 11;
        u16* outqk = (sel == 1) ? Ko : Qo;
#pragma unroll
        for (int k = 0; k < 8; ++k) {
            int cid = tid + k * 512;                   // 0..4095
            int row = cid >> 5, c = cid & 31;          // logical chunk 0..31
            int pc = (c & 24) | ((c & 7) ^ (row & 7));
            uint4 v = *(const uint4*)&Es[row * 256 + pc * 8];
            int h = ((n0 & 1023) >> 6) + (c >> 3);
            int d = (c & 7) * 8;
            int t = (m0 + row) & (T_ - 1);
            *(uint4*)&outqk[((size_t)(bb * NH_ + h) * T_ + t) * HD_ + d] = v;
        }
    }
}

// =====================================================================
// 128x128 GEMM core, 4 waves, BK=64, double-buffered 64 KB LDS.
// =====================================================================
__device__ __forceinline__ void gemm_core128(const u16* __restrict__ A,
                                             const u16* __restrict__ Bt,
                                             u16* smem, int m0, int n0, int tid,
                                             floatx4 (&acc)[4][4]) {
    const int wave = tid >> 6, lane = tid & 63;
    const int ln15 = lane & 15, quad = lane >> 4;
    const int wm = (wave & 1) * 64, wn = (wave >> 1) * 64;
    const int l8 = lane & 7, ld8 = lane >> 3;
    const int sgc = (l8 ^ ld8) * 8;
    const int K = DIM_;

    const u16* aS = A + (size_t)(m0 + wave * 32 + ld8) * K + sgc;
    const u16* bS = Bt + (size_t)(n0 + wave * 32 + ld8) * K + sgc;

    auto stage = [&](int k0, u16* buf) {               // 8 loads/thread
#pragma unroll
        for (int it = 0; it < 4; ++it) {
            async_load16(aS + (size_t)(it * 8) * K + k0,
                         buf + (wave * 32 + it * 8) * 64);
            async_load16(bS + (size_t)(it * 8) * K + k0,
                         buf + 8192 + (wave * 32 + it * 8) * 64);
        }
    };
    auto compute = [&](const u16* buf, int c4) {
        short8 af[4], bfv[4];
#pragma unroll
        for (int i = 0; i < 4; ++i) {
            int row = wm + i * 16 + ln15;
            af[i] = *(const short8*)&buf[row * 64 + (((c4 + quad) ^ (row & 7)) << 3)];
        }
#pragma unroll
        for (int j = 0; j < 4; ++j) {
            int row = wn + j * 16 + ln15;
            bfv[j] = *(const short8*)&buf[8192 + row * 64 + (((c4 + quad) ^ (row & 7)) << 3)];
        }
        __builtin_amdgcn_s_setprio(1);
#pragma unroll
        for (int i = 0; i < 4; ++i)
#pragma unroll
            for (int j = 0; j < 4; ++j)
                acc[i][j] = __builtin_amdgcn_mfma_f32_16x16x32_bf16(
                    af[i], bfv[j], acc[i][j], 0, 0, 0);
        __builtin_amdgcn_s_setprio(0);
    };

    stage(0, smem);
#pragma unroll 1
    for (int t = 0; t < NT_; ++t) {
        asm volatile("s_waitcnt vmcnt(0)" ::: "memory");
        __builtin_amdgcn_s_barrier();
        asm volatile("" ::: "memory");
        if (t + 1 < NT_) stage((t + 1) * 64, smem + ((t + 1) & 1) * 16384);
        const u16* cur = smem + (t & 1) * 16384;
        compute(cur, 0);
        compute(cur, 4);
        asm volatile("" ::: "memory");
    }
}

// ---------- out-proj GEMM, 128x128 core, f32 output ----------
__global__ __launch_bounds__(256, 4) void gemm_proj(const u16* __restrict__ A,
                                                    const u16* __restrict__ Bt,
                                                    float* __restrict__ C) {
    __shared__ __align__(16) u16 smem[32768];
    const int tid = threadIdx.x;
    const int bid = blockIdx.x;
    const int local = bid >> 3;                        // 0..63
    const int by = (bid & 7) * 8 + (local & 7);        // row-block 0..63
    const int bx = local >> 3;                         // col-block 0..7
    const int m0 = by * 128, n0 = bx * 128;

    floatx4 acc[4][4] = {};
    gemm_core128(A, Bt, smem, m0, n0, tid, acc);

    const int wave = tid >> 6, lane = tid & 63;
    const int ln15 = lane & 15, quad = lane >> 4;
    const int wm = (wave & 1) * 64, wn = (wave >> 1) * 64;
#pragma unroll
    for (int i = 0; i < 4; ++i)
#pragma unroll
        for (int jj = 0; jj < 4; ++jj)
#pragma unroll
            for (int r = 0; r < 4; ++r) {
                int m = m0 + wm + i * 16 + quad * 4 + r;
                int n = n0 + wn + jj * 16 + ln15;
                C[(size_t)m * DIM_ + n] = acc[i][jj][r];
            }
}

// ---------- flash attention: one 64-row q-tile per block, heavy-first ----
// Body identical to the verified R2/R4 16-row/wave kernel (swapped QK^T,
// in-register cvt_pk+permlane P transform, LDS-staged dbuf K/V). Grid
// decomposition changed ONLY: 2048 blocks = 32 tiles x 64 bh, heavy
// tiles (tidx=31) first, light ones backfill the scheduler tail.
// 32 KB LDS -> 5 blocks/CU co-resident (vs 4 with the paired grid);
// variable block lengths desynchronize waves -> better stall filling.
// bh = bid & 63: each XCD pinned to 8 bh = 4 MB K/V = its L2.
__global__ __launch_bounds__(256, 5) void attn_kernel(const u16* __restrict__ Q,
                                                      const u16* __restrict__ Kh,
                                                      const u16* __restrict__ Vt,
                                                      u16* __restrict__ Y) {
    __shared__ __align__(16) u16 Kl[2][64 * 64];
    __shared__ __align__(16) u16 Vl[2][64 * 64];
    const int tid = threadIdx.x, wave = tid >> 6, lane = tid & 63;
    const int ln15 = lane & 15, quad = lane >> 4;
    const int bid = blockIdx.x;
    const int tidx = 31 - (bid >> 6);                  // q-tile 0..31, heavy first
    const int bh = bid & 63;
    const int b = bh >> 4, h = bh & 15;
    const int l8 = lane & 7, ld8 = lane >> 3;
    const int sgc = l8 ^ ld8;                          // swizzled source chunk

    const u16* kbase = Kh + (size_t)bh * T_ * HD_;
    const u16* vbase = Vt + (size_t)bh * HD_ * T_;
    const short8 ones = {0x3F80, 0x3F80, 0x3F80, 0x3F80,
                         0x3F80, 0x3F80, 0x3F80, 0x3F80};
    const int srow = wave * 16;

    const int q0 = tidx * 64;
    const int bm = q0 + srow;

    const u16* qp = Q + ((size_t)bh * T_ + bm + ln15) * HD_;
    short8 qf0 = *(const short8*)(qp + quad * 8);
    short8 qf1 = *(const short8*)(qp + 32 + quad * 8);

    floatx4 o[5] = {};                                 // 0..3 = d-cols, 4 = rowsum

#pragma unroll
    for (int it = 0; it < 2; ++it) {
        int r = srow + it * 8;
        async_load16(kbase + (size_t)(r + ld8) * HD_ + sgc * 8, &Kl[0][r * 64]);
        async_load16(vbase + (size_t)(r + ld8) * T_ + sgc * 8, &Vl[0][r * 64]);
    }

    for (int kt = 0; kt <= tidx; ++kt) {
        const int cur = kt & 1;
        __syncthreads();                               // publishes tile kt
        if (kt < tidx) {                               // prefetch kt+1 (overlaps)
            const int kn = (kt + 1) * 64;
#pragma unroll
            for (int it = 0; it < 2; ++it) {
                int r = srow + it * 8;
                async_load16(kbase + (size_t)(kn + r + ld8) * HD_ + sgc * 8,
                             &Kl[cur ^ 1][r * 64]);
                async_load16(vbase + (size_t)(r + ld8) * T_ + kn + sgc * 8,
                             &Vl[cur ^ 1][r * 64]);
            }
        }
        // ---- S^T = K x Q : lane holds qrow=ln15, keys nt*16+quad*4+r ----
        floatx4 s[4] = {};
        __builtin_amdgcn_s_setprio(1);
#pragma unroll
        for (int nt = 0; nt < 4; ++nt) {
            int row = nt * 16 + ln15;
            short8 kf0 = *(const short8*)&Kl[cur][row * 64 + ((quad ^ (row & 7)) << 3)];
            short8 kf1 = *(const short8*)&Kl[cur][row * 64 + (((4 + quad) ^ (row & 7)) << 3)];
            s[nt] = __builtin_amdgcn_mfma_f32_16x16x32_bf16(kf0, qf0, s[nt], 0, 0, 0);
            s[nt] = __builtin_amdgcn_mfma_f32_16x16x32_bf16(kf1, qf1, s[nt], 0, 0, 0);
        }
        __builtin_amdgcn_s_setprio(0);
        if (kt == tidx) {                              // diagonal tile: causal mask
            const int lim = srow + ln15;
#pragma unroll
            for (int nt = 0; nt < 4; ++nt) {
                int key = nt * 16 + quad * 4;
#pragma unroll
                for (int r = 0; r < 4; ++r)
                    s[nt][r] = (key + r > lim) ? 0.f : fexp2(s[nt][r]);
            }
        } else {
#pragma unroll
            for (int nt = 0; nt < 4; ++nt)
#pragma unroll
                for (int r = 0; r < 4; ++r) s[nt][r] = fexp2(s[nt][r]);
        }
        // ---- in-register C/D -> A-operand transform (cvt_pk + permlane) ----
        unsigned x0 = cvtpk_bf16(s[0][0], s[0][1]);
        unsigned x1 = cvtpk_bf16(s[1][0], s[1][1]);
        unsigned y0 = cvtpk_bf16(s[0][2], s[0][3]);
        unsigned y1 = cvtpk_bf16(s[1][2], s[1][3]);
        unsigned x2 = cvtpk_bf16(s[2][0], s[2][1]);
        unsigned x3 = cvtpk_bf16(s[3][0], s[3][1]);
        unsigned y2 = cvtpk_bf16(s[2][2], s[2][3]);
        unsigned y3 = cvtpk_bf16(s[3][2], s[3][3]);
        permlane32_swap(x0, x1); permlane16_swap(x0, x1);
        permlane32_swap(y0, y1); permlane16_swap(y0, y1);
        permlane32_swap(x2, x3); permlane16_swap(x2, x3);
        permlane32_swap(y2, y3); permlane16_swap(y2, y3);
        union { unsigned u[4]; short8 s8; } pk0, pk1;
        pk0.u[0] = x0; pk0.u[1] = y0; pk0.u[2] = x1; pk0.u[3] = y1;
        pk1.u[0] = x2; pk1.u[1] = y2; pk1.u[2] = x3; pk1.u[3] = y3;
        // ---- PV + rowsum ----
        __builtin_amdgcn_s_setprio(1);
#pragma unroll
        for (int nt = 0; nt < 4; ++nt) {
            int row = nt * 16 + ln15;
            short8 vf0 = *(const short8*)&Vl[cur][row * 64 + ((quad ^ (row & 7)) << 3)];
            short8 vf1 = *(const short8*)&Vl[cur][row * 64 + (((4 + quad) ^ (row & 7)) << 3)];
            o[nt] = __builtin_amdgcn_mfma_f32_16x16x32_bf16(pk0.s8, vf0, o[nt], 0, 0, 0);
            o[nt] = __builtin_amdgcn_mfma_f32_16x16x32_bf16(pk1.s8, vf1, o[nt], 0, 0, 0);
        }
        o[4] = __builtin_amdgcn_mfma_f32_16x16x32_bf16(pk0.s8, ones, o[4], 0, 0, 0);
        o[4] = __builtin_amdgcn_mfma_f32_16x16x32_bf16(pk1.s8, ones, o[4], 0, 0, 0);
        __builtin_amdgcn_s_setprio(0);
    }
#pragma unroll
    for (int r = 0; r < 4; ++r) {
        float inv = 1.f / o[4][r];
        int row = bm + quad * 4 + r;
        u16* yp = Y + ((size_t)(b * T_ + row)) * DIM_ + h * HD_;
#pragma unroll
        for (int nt = 0; nt < 4; ++nt)
            yp[nt * 16 + ln15] = f2bf(o[nt][r] * inv);
    }
}

// ---------- launch ----------
extern "C" void kernel_launch(void* const* d_in, const int* in_sizes, int n_in,
                              void* d_out, int out_size, void* d_ws, size_t ws_size,
                              hipStream_t stream) {
    const float* x     = (const float*)d_in[0];
    const float* Wqkv  = (const float*)d_in[1];
    const float* Wproj = (const float*)d_in[2];
    float* out = (float*)d_out;
    char* ws = (char*)d_ws;

    const size_t SZ_XB  = (size_t)M_ * DIM_ * 2;       // 16 MB
    const size_t SZ_WQT = (size_t)NQKV * DIM_ * 2;     // 6 MB
    const size_t SZ_WPT = (size_t)DIM_ * DIM_ * 2;     // 2 MB
    const size_t SZ_Q   = SZ_XB;                       // 16 MB each: Q,K,(unused),Vt
    const size_t SZ_TAB = (size_t)T_ * 32 * 4;         // 256 KB

    u16*   xb   = (u16*)(ws);
    u16*   wqt  = (u16*)(ws + SZ_XB);
    u16*   wpt  = (u16*)(ws + SZ_XB + SZ_WQT);
    u16*   qb   = (u16*)(ws + SZ_XB + SZ_WQT + SZ_WPT);
    u16*   kb   = (u16*)(ws + SZ_XB + SZ_WQT + SZ_WPT + SZ_Q);
    u16*   vtb  = (u16*)(ws + SZ_XB + SZ_WQT + SZ_WPT + 3 * SZ_Q);
    float* tabc = (float*)(ws + SZ_XB + SZ_WQT + SZ_WPT + 4 * SZ_Q);
    float* tabs = (float*)(ws + SZ_XB + SZ_WQT + SZ_WPT + 4 * SZ_Q + SZ_TAB);
    u16*   yb   = xb;                                  // reuse xb after qkv GEMM

    // fused preprocessing (1 launch instead of 4)
    preproc<<<12544, 256, 0, stream>>>(x, Wqkv, Wproj, xb, wqt, wpt, tabc, tabs);
    // 768 blocks = 3 full epochs at 1 block/CU; writes Vt directly
    gemm_qkv<<<768, 512, 0, stream>>>(xb, wqt, tabc, tabs, qb, kb, vtb);
    // 2048 blocks (32 tiles x 64 bh), heavy tiles first, 5 blocks/CU
    attn_kernel<<<2048, 256, 0, stream>>>(qb, kb, vtb, yb);
    // 512 blocks = exactly 1 fill round at 2 blocks/CU
    gemm_proj<<<512, 256, 0, stream>>>(yb, wpt, out);
}